// Round 5
// baseline (3191.681 us; speedup 1.0000x reference)
//
#include <hip/hip_runtime.h>
#include <hip/hip_bf16.h>
#include <math.h>

#define BS   4096
#define ZD   512
#define HIDN 1024
#define ZINN 128
#define NST  32
#define NP   3072   // 3*HIDN, gate-interleaved column space (groups of 32)

typedef unsigned short u16;
typedef __bf16 bf16x8 __attribute__((ext_vector_type(8)));
typedef float f32x4 __attribute__((ext_vector_type(4)));
typedef float f32x16 __attribute__((ext_vector_type(16)));

static __device__ __forceinline__ u16 bf_bits(float v) {
  __bf16 b = (__bf16)v;
  return __builtin_bit_cast(unsigned short, b);
}
static __device__ __forceinline__ float bf_val(float v) {
  return (float)(__bf16)v;
}

// async global -> LDS, 16 bytes per lane. LDS dest = wave-uniform base + lane*16.
static __device__ __forceinline__ void ld_lds16(const u16* g, u16* l) {
  __builtin_amdgcn_global_load_lds(
      (const __attribute__((address_space(1))) void*)g,
      (__attribute__((address_space(3))) void*)l, 16, 0, 0);
}

// W' row w -> original W_hh/W_ih row. w = g*96 + j*32 + m  ->  j*1024 + g*32 + m
static __device__ __forceinline__ int r_orig(int w) {
  const int g = w / 96;
  const int rem = w - g * 96;
  const int j = rem >> 5, m = rem & 31;
  return j * 1024 + g * 32 + m;
}

// ---------------- prep kernels ----------------

__global__ void k_split(const float* __restrict__ s, u16* __restrict__ hi,
                        u16* __restrict__ lo, int n) {
  int i = blockIdx.x * 256 + threadIdx.x;
  if (i >= n) return;
  float v = s[i];
  float h = bf_val(v);
  hi[i] = bf_bits(v);
  lo[i] = bf_bits(v - h);
}

// W_hh split with gate-interleaved row reorder
__global__ void k_split_whh(const float* __restrict__ W_hh, u16* __restrict__ hi,
                            u16* __restrict__ lo) {
  int i = blockIdx.x * 256 + threadIdx.x;
  if (i >= NP * HIDN) return;
  const int w = i >> 10, k = i & 1023;
  const float v = W_hh[(size_t)r_orig(w) * HIDN + k];
  const float h = bf_val(v);
  hi[i] = bf_bits(v);
  lo[i] = bf_bits(v - h);
}

// W_ih[:,3:131] -> split (reordered rows); W_ih[:,0:3] -> wtok (reordered); cb0 (reordered)
__global__ void k_prep_wih(const float* __restrict__ W_ih, const float* __restrict__ b_ih,
                           const float* __restrict__ b_hh,
                           u16* __restrict__ whi, u16* __restrict__ wlo,
                           float* __restrict__ wtok, float* __restrict__ cb0) {
  int i = blockIdx.x * 256 + threadIdx.x;
  if (i < NP * 128) {
    const int w = i >> 7, c = i & 127;
    const int r = r_orig(w);
    const float v = W_ih[r * 131 + 3 + c];
    const float h = bf_val(v);
    whi[i] = bf_bits(v);
    wlo[i] = bf_bits(v - h);
  }
  if (i < NP * 3) {
    const int w = i / 3, s = i - w * 3;
    wtok[i] = W_ih[r_orig(w) * 131 + s];
  }
  if (i < NP) {
    const int r = r_orig(i);
    cb0[i] = b_ih[r] + (r < 2048 ? b_hh[r] : 0.0f);
  }
}

__global__ void k_token_init(const float* __restrict__ init_input, float* __restrict__ token) {
  int i = blockIdx.x * 256 + threadIdx.x;
  if (i < BS * 4) token[i] = ((i & 3) < 3) ? init_input[i & 3] : 0.0f;
}

// ---------------- generic split-3 GEMM (prep only): C = A*B^T (+bias) ----------------
template <bool SPLIT_OUT>
__global__ __launch_bounds__(256) void k_gemm(
    const u16* __restrict__ Ahi, const u16* __restrict__ Alo,
    const u16* __restrict__ Bhi, const u16* __restrict__ Blo,
    const float* __restrict__ bias,
    float* __restrict__ C, u16* __restrict__ Chi, u16* __restrict__ Clo,
    int N, int K) {
  __shared__ __align__(16) u16 sAhi[128 * 64];
  __shared__ __align__(16) u16 sAlo[128 * 64];
  __shared__ __align__(16) u16 sBhi[128 * 64];
  __shared__ __align__(16) u16 sBlo[128 * 64];

  const int t = threadIdx.x;
  const int row0 = blockIdx.y * 128, col0 = blockIdx.x * 128;
  const int wave = t >> 6, lane = t & 63;
  const int w64 = wave * 64;
  const int wm = (wave & 1) * 64, wn = (wave >> 1) * 64;
  const int lm = lane & 15, lq = lane >> 4;
  const int pb = lm & 7;

  f32x4 acc[4][4] = {};

  int sm[4], skc[4], sub[4];
#pragma unroll
  for (int i = 0; i < 4; ++i) {
    const int u = i * 256 + t;
    sm[i] = u >> 3;
    skc[i] = (u & 7) ^ (sm[i] & 7);
    sub[i] = (i * 256 + w64) * 8;
  }

  const int nk = K >> 6;
  for (int kt = 0; kt < nk; ++kt) {
    const int k0 = kt << 6;
    __syncthreads();
#pragma unroll
    for (int i = 0; i < 4; ++i) {
      const size_t ga = (size_t)(row0 + sm[i]) * K + k0 + skc[i] * 8;
      const size_t gb = (size_t)(col0 + sm[i]) * K + k0 + skc[i] * 8;
      ld_lds16(Ahi + ga, &sAhi[sub[i]]);
      ld_lds16(Alo + ga, &sAlo[sub[i]]);
      ld_lds16(Bhi + gb, &sBhi[sub[i]]);
      ld_lds16(Blo + gb, &sBlo[sub[i]]);
    }
    __syncthreads();
#pragma unroll
    for (int kk = 0; kk < 2; ++kk) {
      const int pos = ((kk * 4 + lq) ^ pb) * 8;
      bf16x8 ah[4], al[4], bh[4], bl[4];
#pragma unroll
      for (int i = 0; i < 4; ++i) {
        const int ma = (wm + i * 16 + lm) * 64;
        const int mb = (wn + i * 16 + lm) * 64;
        ah[i] = *(const bf16x8*)&sAhi[ma + pos];
        al[i] = *(const bf16x8*)&sAlo[ma + pos];
        bh[i] = *(const bf16x8*)&sBhi[mb + pos];
        bl[i] = *(const bf16x8*)&sBlo[mb + pos];
      }
#pragma unroll
      for (int i = 0; i < 4; ++i)
#pragma unroll
        for (int j = 0; j < 4; ++j) {
          acc[i][j] = __builtin_amdgcn_mfma_f32_16x16x32_bf16(ah[i], bh[j], acc[i][j], 0, 0, 0);
          acc[i][j] = __builtin_amdgcn_mfma_f32_16x16x32_bf16(al[i], bh[j], acc[i][j], 0, 0, 0);
          acc[i][j] = __builtin_amdgcn_mfma_f32_16x16x32_bf16(ah[i], bl[j], acc[i][j], 0, 0, 0);
        }
    }
  }

#pragma unroll
  for (int i = 0; i < 4; ++i) {
    const int grow = row0 + wm + i * 16 + lq * 4;
#pragma unroll
    for (int j = 0; j < 4; ++j) {
      const int gcol = col0 + wn + j * 16 + lm;
      const float bs = bias ? bias[gcol] : 0.0f;
#pragma unroll
      for (int d = 0; d < 4; ++d) {
        const float v = acc[i][j][d] + bs;
        const size_t idx = (size_t)(grow + d) * N + gcol;
        C[idx] = v;
        if (SPLIT_OUT) {
          const float h = bf_val(v);
          Chi[idx] = bf_bits(v);
          Clo[idx] = bf_bits(v - h);
        }
      }
    }
  }
}

// ---------------- fused gh-GEMM + GRU gate kernel (v3) ----------------
// 128(M) x 192(N') block, 4 waves, wave 64x96 via 32x32x16 MFMA (2 i x 3 j tiles;
// the 3 j-tiles ARE the r/u/n gates for one 32-col group). BK=32, double-buffered
// LDS (2 x 40 KB): stage kt+1 async while computing kt; one barrier per kt so the
// vmcnt drain lands after a full compute phase. XOR swizzle pos = c ^ ((row>>1)&3)
// keeps the 32x32 fragment ds_read_b128 balanced across all 8 bank groups.
__global__ __launch_bounds__(256, 2) void k_fused(
    const u16* __restrict__ Ahi, const u16* __restrict__ Alo,   // h splits [4096][1024]
    const u16* __restrict__ Bhi, const u16* __restrict__ Blo,   // Whh' splits [3072][1024]
    const float* __restrict__ C0,                               // [4096][3072] W'-order
    const float* __restrict__ token,                            // [4096][4]
    const float* __restrict__ wtok,                             // [3072][3] W'-order
    const float* __restrict__ b_hh,                             // original [3072]
    const float* __restrict__ h_in, float* __restrict__ h_out,
    u16* __restrict__ ho_hi, u16* __restrict__ ho_lo) {
  const int K = HIDN;
  __shared__ __align__(16) u16 sAhi[2][128 * 32];
  __shared__ __align__(16) u16 sAlo[2][128 * 32];
  __shared__ __align__(16) u16 sBhi[2][192 * 32];
  __shared__ __align__(16) u16 sBlo[2][192 * 32];

  const int t = threadIdx.x;
  const int wave = t >> 6, lane = t & 63;
  const int row0 = blockIdx.y * 128;
  const int colW0 = blockIdx.x * 192;
  const int lm32 = lane & 31, hi5 = lane >> 5;

  f32x16 acc[2][3] = {};

  // staging decomposition: units of 8 u16; per row 4 chunk-positions,
  // position p holds global chunk p ^ ((row>>1)&3).
  int aoff[2], au[2], boff[3], bu[3];
#pragma unroll
  for (int i = 0; i < 2; ++i) {
    const int u = i * 256 + wave * 64 + lane;
    const int r = u >> 2;
    const int gc = (u & 3) ^ ((r >> 1) & 3);
    aoff[i] = (row0 + r) * K + gc * 8;
    au[i] = u * 8;
  }
#pragma unroll
  for (int i = 0; i < 3; ++i) {
    const int u = i * 256 + wave * 64 + lane;
    const int r = u >> 2;
    const int gc = (u & 3) ^ ((r >> 1) & 3);
    boff[i] = (colW0 + r) * K + gc * 8;
    bu[i] = u * 8;
  }

  // fragment read bases: m-row per i-tile, n-row per j-tile (gate)
  int ami[2], aswz[2], bnj[3], bswz[3];
#pragma unroll
  for (int i = 0; i < 2; ++i) {
    const int m = (wave & 1) * 64 + i * 32 + lm32;
    ami[i] = m * 4;
    aswz[i] = (m >> 1) & 3;
  }
#pragma unroll
  for (int j = 0; j < 3; ++j) {
    const int n = (wave >> 1) * 96 + j * 32 + lm32;
    bnj[j] = n * 4;
    bswz[j] = (n >> 1) & 3;
  }

  // prologue: stage kt=0 into buf 0
#pragma unroll
  for (int i = 0; i < 2; ++i) {
    ld_lds16(Ahi + aoff[i], &sAhi[0][au[i]]);
    ld_lds16(Alo + aoff[i], &sAlo[0][au[i]]);
  }
#pragma unroll
  for (int i = 0; i < 3; ++i) {
    ld_lds16(Bhi + boff[i], &sBhi[0][bu[i]]);
    ld_lds16(Blo + boff[i], &sBlo[0][bu[i]]);
  }
  __syncthreads();

  for (int kt = 0; kt < 32; ++kt) {
    const int buf = kt & 1;
    if (kt < 31) {
      const int k0 = (kt + 1) << 5;
#pragma unroll
      for (int i = 0; i < 2; ++i) {
        ld_lds16(Ahi + aoff[i] + k0, &sAhi[buf ^ 1][au[i]]);
        ld_lds16(Alo + aoff[i] + k0, &sAlo[buf ^ 1][au[i]]);
      }
#pragma unroll
      for (int i = 0; i < 3; ++i) {
        ld_lds16(Bhi + boff[i] + k0, &sBhi[buf ^ 1][bu[i]]);
        ld_lds16(Blo + boff[i] + k0, &sBlo[buf ^ 1][bu[i]]);
      }
    }
#pragma unroll
    for (int s = 0; s < 2; ++s) {
      const int c = s * 2 + hi5;
      bf16x8 ah[2], al[2], bh[3], bl[3];
#pragma unroll
      for (int i = 0; i < 2; ++i) {
        const int un = (ami[i] + (c ^ aswz[i])) * 8;
        ah[i] = *(const bf16x8*)&sAhi[buf][un];
        al[i] = *(const bf16x8*)&sAlo[buf][un];
      }
#pragma unroll
      for (int j = 0; j < 3; ++j) {
        const int un = (bnj[j] + (c ^ bswz[j])) * 8;
        bh[j] = *(const bf16x8*)&sBhi[buf][un];
        bl[j] = *(const bf16x8*)&sBlo[buf][un];
      }
#pragma unroll
      for (int i = 0; i < 2; ++i)
#pragma unroll
        for (int j = 0; j < 3; ++j) {
          acc[i][j] = __builtin_amdgcn_mfma_f32_32x32x16_bf16(ah[i], bh[j], acc[i][j], 0, 0, 0);
          acc[i][j] = __builtin_amdgcn_mfma_f32_32x32x16_bf16(al[i], bh[j], acc[i][j], 0, 0, 0);
          acc[i][j] = __builtin_amdgcn_mfma_f32_32x32x16_bf16(ah[i], bl[j], acc[i][j], 0, 0, 0);
        }
    }
    __syncthreads();
  }

  // ---- fused GRU epilogue (exact f32) ----
  // C/D layout (32x32): col = lane&31, row = (reg&3) + 8*(reg>>2) + 4*(lane>>5)
  const int g = blockIdx.x * 2 + (wave >> 1);  // 32-col group
  const int c = g * 32 + lm32;                 // h-col
  const int w0 = g * 96 + lm32;                // W'-row of r-gate
  float wt[3][3];
#pragma unroll
  for (int j = 0; j < 3; ++j) {
    wt[j][0] = wtok[(w0 + j * 32) * 3 + 0];
    wt[j][1] = wtok[(w0 + j * 32) * 3 + 1];
    wt[j][2] = wtok[(w0 + j * 32) * 3 + 2];
  }
  const float bn = b_hh[2048 + c];
#pragma unroll
  for (int i = 0; i < 2; ++i) {
#pragma unroll
    for (int r = 0; r < 16; ++r) {
      const int row = row0 + (wave & 1) * 64 + i * 32 + (r & 3) + 8 * (r >> 2) + 4 * hi5;
      const float4 tk = *(const float4*)&token[row * 4];
      const size_t cb = (size_t)row * NP;
      const float pr = C0[cb + w0] + acc[i][0][r] + tk.x * wt[0][0] + tk.y * wt[0][1] + tk.z * wt[0][2];
      const float pu = C0[cb + w0 + 32] + acc[i][1][r] + tk.x * wt[1][0] + tk.y * wt[1][1] + tk.z * wt[1][2];
      const float pn = C0[cb + w0 + 64] + tk.x * wt[2][0] + tk.y * wt[2][1] + tk.z * wt[2][2];
      const float hn = acc[i][2][r] + bn;
      const float rr = 1.0f / (1.0f + expf(-pr));
      const float uu = 1.0f / (1.0f + expf(-pu));
      const float nn = tanhf(pn + rr * hn);
      const size_t hidx = (size_t)row * HIDN + c;
      const float ho = h_in[hidx];
      const float hv = (1.0f - uu) * nn + uu * ho;
      h_out[hidx] = hv;
      const float hh = bf_val(hv);
      ho_hi[hidx] = bf_bits(hv);
      ho_lo[hidx] = bf_bits(hv - hh);
    }
  }
}

// ---------------- per-step output kernel ----------------
__global__ __launch_bounds__(256) void k_out(
    const float* __restrict__ h, const float* __restrict__ W_out,
    const float* __restrict__ b_out,
    float* __restrict__ out, float* __restrict__ token, int step) {
  const int wave = threadIdx.x >> 6, lane = threadIdx.x & 63;
  const int row = blockIdx.x * 4 + wave;
  const float4* hp = (const float4*)(h + (size_t)row * 1024);
  const float4* w0p = (const float4*)(W_out);
  const float4* w1p = (const float4*)(W_out + 1024);
  const float4* w2p = (const float4*)(W_out + 2048);
  float s0 = 0.f, s1 = 0.f, s2 = 0.f;
#pragma unroll
  for (int c = 0; c < 4; ++c) {
    const int k = lane + 64 * c;
    const float4 hv = hp[k];
    const float4 a = w0p[k], bq = w1p[k], cq = w2p[k];
    s0 += hv.x * a.x + hv.y * a.y + hv.z * a.z + hv.w * a.w;
    s1 += hv.x * bq.x + hv.y * bq.y + hv.z * bq.z + hv.w * bq.w;
    s2 += hv.x * cq.x + hv.y * cq.y + hv.z * cq.z + hv.w * cq.w;
  }
#pragma unroll
  for (int off = 32; off > 0; off >>= 1) {
    s0 += __shfl_xor(s0, off, 64);
    s1 += __shfl_xor(s1, off, 64);
    s2 += __shfl_xor(s2, off, 64);
  }
  if (lane == 0) {
    const float o0 = s0 + b_out[0];
    const float o1 = s1 + b_out[1];
    const float o2 = s2 + b_out[2];
    const float bass = 1.0f / (1.0f + expf(-o0));
    const float rhy = 1.0f / (1.0f + expf(-o2));
    const size_t ob = ((size_t)row * NST + step) * 3;
    out[ob + 0] = bass;
    out[ob + 1] = o1;
    out[ob + 2] = rhy;
    token[row * 4 + 0] = bass;
    token[row * 4 + 1] = o1;
    token[row * 4 + 2] = (rhy > 0.5f) ? 1.0f : 0.0f;
  }
}

// ---------------- host ----------------
extern "C" void kernel_launch(void* const* d_in, const int* in_sizes, int n_in,
                              void* d_out, int out_size, void* d_ws, size_t ws_size,
                              hipStream_t stream) {
  const float* z = (const float*)d_in[0];
  const float* W_zh = (const float*)d_in[3];
  const float* b_zh = (const float*)d_in[4];
  const float* W_zi = (const float*)d_in[5];
  const float* b_zi = (const float*)d_in[6];
  const float* W_ih = (const float*)d_in[7];
  const float* b_ih = (const float*)d_in[8];
  const float* W_hh = (const float*)d_in[9];
  const float* b_hh = (const float*)d_in[10];
  const float* W_out = (const float*)d_in[11];
  const float* b_out = (const float*)d_in[12];
  const float* init_input = (const float*)d_in[13];
  float* out = (float*)d_out;

  char* p = (char*)d_ws;
  auto alloc = [&](size_t bytes) {
    char* q = p;
    p += (bytes + 255) & ~(size_t)255;
    return q;
  };
  float* h[2];
  u16 *h_hi[2], *h_lo[2];
  for (int s = 0; s < 2; ++s) {
    h[s] = (float*)alloc((size_t)BS * HIDN * 4);
    h_hi[s] = (u16*)alloc((size_t)BS * HIDN * 2);
    h_lo[s] = (u16*)alloc((size_t)BS * HIDN * 2);
  }
  float* C0 = (float*)alloc((size_t)BS * NP * 4);
  u16* z_hi = (u16*)alloc((size_t)BS * ZD * 2);
  u16* z_lo = (u16*)alloc((size_t)BS * ZD * 2);
  float* zin = (float*)alloc((size_t)BS * ZINN * 4);
  u16* zin_hi = (u16*)alloc((size_t)BS * ZINN * 2);
  u16* zin_lo = (u16*)alloc((size_t)BS * ZINN * 2);
  u16* Wzh_hi = (u16*)alloc((size_t)HIDN * ZD * 2);
  u16* Wzh_lo = (u16*)alloc((size_t)HIDN * ZD * 2);
  u16* Wzi_hi = (u16*)alloc((size_t)ZINN * ZD * 2);
  u16* Wzi_lo = (u16*)alloc((size_t)ZINN * ZD * 2);
  u16* Wihz_hi = (u16*)alloc((size_t)NP * ZINN * 2);
  u16* Wihz_lo = (u16*)alloc((size_t)NP * ZINN * 2);
  u16* Whh_hi = (u16*)alloc((size_t)NP * HIDN * 2);
  u16* Whh_lo = (u16*)alloc((size_t)NP * HIDN * 2);
  float* wtok = (float*)alloc((size_t)NP * 3 * 4);
  float* cb0 = (float*)alloc((size_t)NP * 4);
  float* token = (float*)alloc((size_t)BS * 4 * 4);

  // ---- prep ----
  k_split_whh<<<dim3((NP * HIDN + 255) / 256), 256, 0, stream>>>(W_hh, Whh_hi, Whh_lo);
  k_split<<<dim3((HIDN * ZD + 255) / 256), 256, 0, stream>>>(W_zh, Wzh_hi, Wzh_lo, HIDN * ZD);
  k_split<<<dim3((ZINN * ZD + 255) / 256), 256, 0, stream>>>(W_zi, Wzi_hi, Wzi_lo, ZINN * ZD);
  k_split<<<dim3((BS * ZD + 255) / 256), 256, 0, stream>>>(z, z_hi, z_lo, BS * ZD);
  k_prep_wih<<<dim3((NP * 128 + 255) / 256), 256, 0, stream>>>(W_ih, b_ih, b_hh, Wihz_hi, Wihz_lo, wtok, cb0);
  k_token_init<<<dim3((BS * 4 + 255) / 256), 256, 0, stream>>>(init_input, token);

  // ---- prep GEMMs ----
  k_gemm<true><<<dim3(HIDN / 128, BS / 128), 256, 0, stream>>>(
      z_hi, z_lo, Wzh_hi, Wzh_lo, b_zh, h[0], h_hi[0], h_lo[0], HIDN, ZD);
  k_gemm<true><<<dim3(ZINN / 128, BS / 128), 256, 0, stream>>>(
      z_hi, z_lo, Wzi_hi, Wzi_lo, b_zi, zin, zin_hi, zin_lo, ZINN, ZD);
  k_gemm<false><<<dim3(NP / 128, BS / 128), 256, 0, stream>>>(
      zin_hi, zin_lo, Wihz_hi, Wihz_lo, cb0, C0, nullptr, nullptr, NP, ZINN);

  // ---- 32 recurrent steps ----
  for (int t = 0; t < NST; ++t) {
    const int cur = t & 1, nxt = (t + 1) & 1;
    k_fused<<<dim3(NP / 192, BS / 128), 256, 0, stream>>>(
        h_hi[cur], h_lo[cur], Whh_hi, Whh_lo, C0, token, wtok, b_hh,
        h[cur], h[nxt], h_hi[nxt], h_lo[nxt]);
    k_out<<<dim3(BS / 4), 256, 0, stream>>>(h[nxt], W_out, b_out, out, token, t);
  }
  (void)in_sizes; (void)n_in; (void)out_size; (void)ws_size;
}

// Round 6
// 2823.881 us; speedup vs baseline: 1.1302x; 1.1302x over previous
//
#include <hip/hip_runtime.h>
#include <hip/hip_bf16.h>
#include <math.h>

#define BS   4096
#define ZD   512
#define HIDN 1024
#define ZINN 128
#define NST  32
#define NP   3072   // 3*HIDN, gate-interleaved column space (16-col groups)

typedef unsigned short u16;
typedef __bf16 bf16x8 __attribute__((ext_vector_type(8)));
typedef float f32x4 __attribute__((ext_vector_type(4)));

static __device__ __forceinline__ u16 bf_bits(float v) {
  __bf16 b = (__bf16)v;
  return __builtin_bit_cast(unsigned short, b);
}
static __device__ __forceinline__ float bf_val(float v) {
  return (float)(__bf16)v;
}

// async global -> LDS, 16 bytes per lane. LDS dest = wave-uniform base + lane*16.
static __device__ __forceinline__ void ld_lds16(const u16* g, u16* l) {
  __builtin_amdgcn_global_load_lds(
      (const __attribute__((address_space(1))) void*)g,
      (__attribute__((address_space(3))) void*)l, 16, 0, 0);
}

// W' row w -> original W_hh/W_ih row. w = g*48 + j*16 + m  ->  j*1024 + g*16 + m
static __device__ __forceinline__ int r_orig(int w) {
  const int g = w / 48;
  const int rem = w - g * 48;
  const int j = rem >> 4, m = rem & 15;
  return j * 1024 + g * 16 + m;
}

// ---------------- prep kernels ----------------

__global__ void k_split(const float* __restrict__ s, u16* __restrict__ hi,
                        u16* __restrict__ lo, int n) {
  int i = blockIdx.x * 256 + threadIdx.x;
  if (i >= n) return;
  float v = s[i];
  float h = bf_val(v);
  hi[i] = bf_bits(v);
  lo[i] = bf_bits(v - h);
}

// W_hh split with gate-interleaved row reorder
__global__ void k_split_whh(const float* __restrict__ W_hh, u16* __restrict__ hi,
                            u16* __restrict__ lo) {
  int i = blockIdx.x * 256 + threadIdx.x;
  if (i >= NP * HIDN) return;
  const int w = i >> 10, k = i & 1023;
  const float v = W_hh[(size_t)r_orig(w) * HIDN + k];
  const float h = bf_val(v);
  hi[i] = bf_bits(v);
  lo[i] = bf_bits(v - h);
}

// W_ih preprocessing:
//  ru_hi/lo [3072][128]: W_ih[:,3:131] in W'-row order, n-gate rows zeroed (K-fold operand)
//  zn_hi/lo [1024][128]: W_ih n-gate rows, plain order (for C0n prep GEMM)
//  wtok     [3072][3]  : W_ih[:,0:3] in W'-row order
//  cb0ru    [3072]     : b_ih + b_hh for r,u rows (0 for n rows)
__global__ void k_prep_wih(const float* __restrict__ W_ih, const float* __restrict__ b_ih,
                           const float* __restrict__ b_hh,
                           u16* __restrict__ ru_hi, u16* __restrict__ ru_lo,
                           u16* __restrict__ zn_hi, u16* __restrict__ zn_lo,
                           float* __restrict__ wtok, float* __restrict__ cb0ru) {
  int i = blockIdx.x * 256 + threadIdx.x;
  if (i < NP * 128) {
    const int w = i >> 7, c = i & 127;
    const int r = r_orig(w);
    const float v = (r < 2048) ? W_ih[r * 131 + 3 + c] : 0.0f;
    const float h = bf_val(v);
    ru_hi[i] = bf_bits(v);
    ru_lo[i] = bf_bits(v - h);
  }
  if (i < HIDN * 128) {
    const int c = i >> 7, k = i & 127;
    const float v = W_ih[(2048 + c) * 131 + 3 + k];
    const float h = bf_val(v);
    zn_hi[i] = bf_bits(v);
    zn_lo[i] = bf_bits(v - h);
  }
  if (i < NP * 3) {
    const int w = i / 3, s = i - w * 3;
    wtok[i] = W_ih[r_orig(w) * 131 + s];
  }
  if (i < NP) {
    const int r = r_orig(i);
    cb0ru[i] = (r < 2048) ? (b_ih[r] + b_hh[r]) : 0.0f;
  }
}

__global__ void k_token_init(const float* __restrict__ init_input, float* __restrict__ token) {
  int i = blockIdx.x * 256 + threadIdx.x;
  if (i < BS * 4) token[i] = ((i & 3) < 3) ? init_input[i & 3] : 0.0f;
}

// ---------------- generic split-3 GEMM (prep only): C = A*B^T (+bias) ----------------
template <bool SPLIT_OUT>
__global__ __launch_bounds__(256) void k_gemm(
    const u16* __restrict__ Ahi, const u16* __restrict__ Alo,
    const u16* __restrict__ Bhi, const u16* __restrict__ Blo,
    const float* __restrict__ bias,
    float* __restrict__ C, u16* __restrict__ Chi, u16* __restrict__ Clo,
    int N, int K) {
  __shared__ __align__(16) u16 sAhi[128 * 64];
  __shared__ __align__(16) u16 sAlo[128 * 64];
  __shared__ __align__(16) u16 sBhi[128 * 64];
  __shared__ __align__(16) u16 sBlo[128 * 64];

  const int t = threadIdx.x;
  const int row0 = blockIdx.y * 128, col0 = blockIdx.x * 128;
  const int wave = t >> 6, lane = t & 63;
  const int w64 = wave * 64;
  const int wm = (wave & 1) * 64, wn = (wave >> 1) * 64;
  const int lm = lane & 15, lq = lane >> 4;
  const int pb = lm & 7;

  f32x4 acc[4][4] = {};

  int sm[4], skc[4], sub[4];
#pragma unroll
  for (int i = 0; i < 4; ++i) {
    const int u = i * 256 + t;
    sm[i] = u >> 3;
    skc[i] = (u & 7) ^ (sm[i] & 7);
    sub[i] = (i * 256 + w64) * 8;
  }

  const int nk = K >> 6;
  for (int kt = 0; kt < nk; ++kt) {
    const int k0 = kt << 6;
    __syncthreads();
#pragma unroll
    for (int i = 0; i < 4; ++i) {
      const size_t ga = (size_t)(row0 + sm[i]) * K + k0 + skc[i] * 8;
      const size_t gb = (size_t)(col0 + sm[i]) * K + k0 + skc[i] * 8;
      ld_lds16(Ahi + ga, &sAhi[sub[i]]);
      ld_lds16(Alo + ga, &sAlo[sub[i]]);
      ld_lds16(Bhi + gb, &sBhi[sub[i]]);
      ld_lds16(Blo + gb, &sBlo[sub[i]]);
    }
    __syncthreads();
#pragma unroll
    for (int kk = 0; kk < 2; ++kk) {
      const int pos = ((kk * 4 + lq) ^ pb) * 8;
      bf16x8 ah[4], al[4], bh[4], bl[4];
#pragma unroll
      for (int i = 0; i < 4; ++i) {
        const int ma = (wm + i * 16 + lm) * 64;
        const int mb = (wn + i * 16 + lm) * 64;
        ah[i] = *(const bf16x8*)&sAhi[ma + pos];
        al[i] = *(const bf16x8*)&sAlo[ma + pos];
        bh[i] = *(const bf16x8*)&sBhi[mb + pos];
        bl[i] = *(const bf16x8*)&sBlo[mb + pos];
      }
#pragma unroll
      for (int i = 0; i < 4; ++i)
#pragma unroll
        for (int j = 0; j < 4; ++j) {
          acc[i][j] = __builtin_amdgcn_mfma_f32_16x16x32_bf16(ah[i], bh[j], acc[i][j], 0, 0, 0);
          acc[i][j] = __builtin_amdgcn_mfma_f32_16x16x32_bf16(al[i], bh[j], acc[i][j], 0, 0, 0);
          acc[i][j] = __builtin_amdgcn_mfma_f32_16x16x32_bf16(ah[i], bl[j], acc[i][j], 0, 0, 0);
        }
    }
  }

#pragma unroll
  for (int i = 0; i < 4; ++i) {
    const int grow = row0 + wm + i * 16 + lq * 4;
#pragma unroll
    for (int j = 0; j < 4; ++j) {
      const int gcol = col0 + wn + j * 16 + lm;
      const float bs = bias ? bias[gcol] : 0.0f;
#pragma unroll
      for (int d = 0; d < 4; ++d) {
        const float v = acc[i][j][d] + bs;
        const size_t idx = (size_t)(grow + d) * N + gcol;
        C[idx] = v;
        if (SPLIT_OUT) {
          const float h = bf_val(v);
          Chi[idx] = bf_bits(v);
          Clo[idx] = bf_bits(v - h);
        }
      }
    }
  }
}

// ---------------- fused [h|zin]-GEMM + GRU gate kernel (v4) ----------------
// Round-4 structure: 128(M) x 192(N') block, BK=64, 4 waves each 64x96 (acc[4][6]),
// XOR-swizzled staging + conflict-free ds_read_b128. K extended to 1152:
// kt 0..15 = h @ Whh' (all gates); 2 peeled tiles = zin @ Wihz'_{r,u} (j%3!=2 only).
// n-gate zin part comes precomputed via C0n (step-invariant). No C0[4096][3072].
__global__ __launch_bounds__(256, 2) void k_fused(
    const u16* __restrict__ Ahi, const u16* __restrict__ Alo,    // h splits [4096][1024]
    const u16* __restrict__ Zhi, const u16* __restrict__ Zlo,    // zin splits [4096][128]
    const u16* __restrict__ Bhi, const u16* __restrict__ Blo,    // Whh' splits [3072][1024]
    const u16* __restrict__ BZhi, const u16* __restrict__ BZlo,  // Wihz'' splits [3072][128]
    const float* __restrict__ C0n,                               // [4096][1024]
    const float* __restrict__ token,                             // [4096][4]
    const float* __restrict__ wtok,                              // [3072][3] W'-order
    const float* __restrict__ cb0ru,                             // [3072] W'-order
    const float* __restrict__ b_hh,                              // original [3072]
    const float* __restrict__ h_in, float* __restrict__ h_out,
    u16* __restrict__ ho_hi, u16* __restrict__ ho_lo) {
  __shared__ __align__(16) u16 sAhi[128 * 64];
  __shared__ __align__(16) u16 sAlo[128 * 64];
  __shared__ __align__(16) u16 sBhi[192 * 64];
  __shared__ __align__(16) u16 sBlo[192 * 64];

  const int t = threadIdx.x;
  const int wave = t >> 6, lane = t & 63;
  const int w64 = wave * 64;
  const int row0 = blockIdx.y * 128;
  const int colW0 = blockIdx.x * 192;
  const int wm = (wave & 1) * 64;
  const int wn = (wave >> 1) * 96;
  const int lm = lane & 15, lq = lane >> 4;
  const int pb = lm & 7;

  f32x4 acc[4][6] = {};

  // staging decomposition (XOR-swizzled chunk positions), h- and zin-strides
  int aoh[4], aoz[4], aub[4], boh[6], boz[6], bub[6];
#pragma unroll
  for (int i = 0; i < 4; ++i) {
    const int u = i * 256 + t;
    const int r = u >> 3;
    const int kc = (u & 7) ^ (r & 7);
    aoh[i] = (row0 + r) * HIDN + kc * 8;
    aoz[i] = (row0 + r) * ZINN + kc * 8;
    aub[i] = (i * 256 + w64) * 8;
  }
#pragma unroll
  for (int i = 0; i < 6; ++i) {
    const int u = i * 256 + t;
    const int r = u >> 3;
    const int kc = (u & 7) ^ (r & 7);
    boh[i] = (colW0 + r) * HIDN + kc * 8;
    boz[i] = (colW0 + r) * ZINN + kc * 8;
    bub[i] = (i * 256 + w64) * 8;
  }

  // main K loop over h (kt 0..15)
  for (int kt = 0; kt < 16; ++kt) {
    const int k0 = kt << 6;
    __syncthreads();
#pragma unroll
    for (int i = 0; i < 4; ++i) {
      ld_lds16(Ahi + aoh[i] + k0, &sAhi[aub[i]]);
      ld_lds16(Alo + aoh[i] + k0, &sAlo[aub[i]]);
    }
#pragma unroll
    for (int i = 0; i < 6; ++i) {
      ld_lds16(Bhi + boh[i] + k0, &sBhi[bub[i]]);
      ld_lds16(Blo + boh[i] + k0, &sBlo[bub[i]]);
    }
    __syncthreads();
#pragma unroll
    for (int kk = 0; kk < 2; ++kk) {
      const int pos = ((kk * 4 + lq) ^ pb) * 8;
      bf16x8 ah[4], al[4], bh[6], bl[6];
#pragma unroll
      for (int i = 0; i < 4; ++i) {
        const int ma = (wm + i * 16 + lm) * 64;
        ah[i] = *(const bf16x8*)&sAhi[ma + pos];
        al[i] = *(const bf16x8*)&sAlo[ma + pos];
      }
#pragma unroll
      for (int j = 0; j < 6; ++j) {
        const int mb = (wn + j * 16 + lm) * 64;
        bh[j] = *(const bf16x8*)&sBhi[mb + pos];
        bl[j] = *(const bf16x8*)&sBlo[mb + pos];
      }
#pragma unroll
      for (int i = 0; i < 4; ++i)
#pragma unroll
        for (int j = 0; j < 6; ++j) {
          acc[i][j] = __builtin_amdgcn_mfma_f32_16x16x32_bf16(ah[i], bh[j], acc[i][j], 0, 0, 0);
          acc[i][j] = __builtin_amdgcn_mfma_f32_16x16x32_bf16(al[i], bh[j], acc[i][j], 0, 0, 0);
          acc[i][j] = __builtin_amdgcn_mfma_f32_16x16x32_bf16(ah[i], bl[j], acc[i][j], 0, 0, 0);
        }
    }
  }

  // peeled zin K-extension (r,u gates only: j in {0,1,3,4})
  for (int kz = 0; kz < 2; ++kz) {
    const int k0 = kz << 6;
    __syncthreads();
#pragma unroll
    for (int i = 0; i < 4; ++i) {
      ld_lds16(Zhi + aoz[i] + k0, &sAhi[aub[i]]);
      ld_lds16(Zlo + aoz[i] + k0, &sAlo[aub[i]]);
    }
#pragma unroll
    for (int i = 0; i < 6; ++i) {
      ld_lds16(BZhi + boz[i] + k0, &sBhi[bub[i]]);
      ld_lds16(BZlo + boz[i] + k0, &sBlo[bub[i]]);
    }
    __syncthreads();
#pragma unroll
    for (int kk = 0; kk < 2; ++kk) {
      const int pos = ((kk * 4 + lq) ^ pb) * 8;
      bf16x8 ah[4], al[4], bh[4], bl[4];
      const int js[4] = {0, 1, 3, 4};
#pragma unroll
      for (int i = 0; i < 4; ++i) {
        const int ma = (wm + i * 16 + lm) * 64;
        ah[i] = *(const bf16x8*)&sAhi[ma + pos];
        al[i] = *(const bf16x8*)&sAlo[ma + pos];
      }
#pragma unroll
      for (int jj = 0; jj < 4; ++jj) {
        const int mb = (wn + js[jj] * 16 + lm) * 64;
        bh[jj] = *(const bf16x8*)&sBhi[mb + pos];
        bl[jj] = *(const bf16x8*)&sBlo[mb + pos];
      }
#pragma unroll
      for (int i = 0; i < 4; ++i)
#pragma unroll
        for (int jj = 0; jj < 4; ++jj) {
          acc[i][js[jj]] = __builtin_amdgcn_mfma_f32_16x16x32_bf16(ah[i], bh[jj], acc[i][js[jj]], 0, 0, 0);
          acc[i][js[jj]] = __builtin_amdgcn_mfma_f32_16x16x32_bf16(al[i], bh[jj], acc[i][js[jj]], 0, 0, 0);
          acc[i][js[jj]] = __builtin_amdgcn_mfma_f32_16x16x32_bf16(ah[i], bl[jj], acc[i][js[jj]], 0, 0, 0);
        }
    }
  }

  // ---- fused GRU epilogue (exact f32); two gate-triples per wave (jt=0,1) ----
#pragma unroll
  for (int jt = 0; jt < 2; ++jt) {
    const int w0 = colW0 + wn + jt * 48 + lm;   // W'-row of r-gate
    const int g = (colW0 + wn + jt * 48) / 48;  // h-col group
    const int c = g * 16 + lm;                  // h-col
    float wt[3][3];
#pragma unroll
    for (int j = 0; j < 3; ++j) {
      wt[j][0] = wtok[(w0 + j * 16) * 3 + 0];
      wt[j][1] = wtok[(w0 + j * 16) * 3 + 1];
      wt[j][2] = wtok[(w0 + j * 16) * 3 + 2];
    }
    const float bn = b_hh[2048 + c];
    const float br = cb0ru[w0];
    const float bu = cb0ru[w0 + 16];
#pragma unroll
    for (int i = 0; i < 4; ++i) {
#pragma unroll
      for (int d = 0; d < 4; ++d) {
        const int row = row0 + wm + i * 16 + lq * 4 + d;
        const float4 tk = *(const float4*)&token[row * 4];
        const float pr = br + acc[i][jt * 3 + 0][d] + tk.x * wt[0][0] + tk.y * wt[0][1] + tk.z * wt[0][2];
        const float pu = bu + acc[i][jt * 3 + 1][d] + tk.x * wt[1][0] + tk.y * wt[1][1] + tk.z * wt[1][2];
        const float pn = C0n[(size_t)row * HIDN + c] + tk.x * wt[2][0] + tk.y * wt[2][1] + tk.z * wt[2][2];
        const float hn = acc[i][jt * 3 + 2][d] + bn;
        const float r = 1.0f / (1.0f + expf(-pr));
        const float u = 1.0f / (1.0f + expf(-pu));
        const float n = tanhf(pn + r * hn);
        const size_t hidx = (size_t)row * HIDN + c;
        const float ho = h_in[hidx];
        const float hv = (1.0f - u) * n + u * ho;
        h_out[hidx] = hv;
        const float hh = bf_val(hv);
        ho_hi[hidx] = bf_bits(hv);
        ho_lo[hidx] = bf_bits(hv - hh);
      }
    }
  }
}

// ---------------- per-step output kernel ----------------
__global__ __launch_bounds__(256) void k_out(
    const float* __restrict__ h, const float* __restrict__ W_out,
    const float* __restrict__ b_out,
    float* __restrict__ out, float* __restrict__ token, int step) {
  const int wave = threadIdx.x >> 6, lane = threadIdx.x & 63;
  const int row = blockIdx.x * 4 + wave;
  const float4* hp = (const float4*)(h + (size_t)row * 1024);
  const float4* w0p = (const float4*)(W_out);
  const float4* w1p = (const float4*)(W_out + 1024);
  const float4* w2p = (const float4*)(W_out + 2048);
  float s0 = 0.f, s1 = 0.f, s2 = 0.f;
#pragma unroll
  for (int c = 0; c < 4; ++c) {
    const int k = lane + 64 * c;
    const float4 hv = hp[k];
    const float4 a = w0p[k], bq = w1p[k], cq = w2p[k];
    s0 += hv.x * a.x + hv.y * a.y + hv.z * a.z + hv.w * a.w;
    s1 += hv.x * bq.x + hv.y * bq.y + hv.z * bq.z + hv.w * bq.w;
    s2 += hv.x * cq.x + hv.y * cq.y + hv.z * cq.z + hv.w * cq.w;
  }
#pragma unroll
  for (int off = 32; off > 0; off >>= 1) {
    s0 += __shfl_xor(s0, off, 64);
    s1 += __shfl_xor(s1, off, 64);
    s2 += __shfl_xor(s2, off, 64);
  }
  if (lane == 0) {
    const float o0 = s0 + b_out[0];
    const float o1 = s1 + b_out[1];
    const float o2 = s2 + b_out[2];
    const float bass = 1.0f / (1.0f + expf(-o0));
    const float rhy = 1.0f / (1.0f + expf(-o2));
    const size_t ob = ((size_t)row * NST + step) * 3;
    out[ob + 0] = bass;
    out[ob + 1] = o1;
    out[ob + 2] = rhy;
    token[row * 4 + 0] = bass;
    token[row * 4 + 1] = o1;
    token[row * 4 + 2] = (rhy > 0.5f) ? 1.0f : 0.0f;
  }
}

// ---------------- host ----------------
extern "C" void kernel_launch(void* const* d_in, const int* in_sizes, int n_in,
                              void* d_out, int out_size, void* d_ws, size_t ws_size,
                              hipStream_t stream) {
  const float* z = (const float*)d_in[0];
  const float* W_zh = (const float*)d_in[3];
  const float* b_zh = (const float*)d_in[4];
  const float* W_zi = (const float*)d_in[5];
  const float* b_zi = (const float*)d_in[6];
  const float* W_ih = (const float*)d_in[7];
  const float* b_ih = (const float*)d_in[8];
  const float* W_hh = (const float*)d_in[9];
  const float* b_hh = (const float*)d_in[10];
  const float* W_out = (const float*)d_in[11];
  const float* b_out = (const float*)d_in[12];
  const float* init_input = (const float*)d_in[13];
  float* out = (float*)d_out;

  char* p = (char*)d_ws;
  auto alloc = [&](size_t bytes) {
    char* q = p;
    p += (bytes + 255) & ~(size_t)255;
    return q;
  };
  float* h[2];
  u16 *h_hi[2], *h_lo[2];
  for (int s = 0; s < 2; ++s) {
    h[s] = (float*)alloc((size_t)BS * HIDN * 4);
    h_hi[s] = (u16*)alloc((size_t)BS * HIDN * 2);
    h_lo[s] = (u16*)alloc((size_t)BS * HIDN * 2);
  }
  float* C0n = (float*)alloc((size_t)BS * HIDN * 4);
  u16* z_hi = (u16*)alloc((size_t)BS * ZD * 2);
  u16* z_lo = (u16*)alloc((size_t)BS * ZD * 2);
  float* zin = (float*)alloc((size_t)BS * ZINN * 4);
  u16* zin_hi = (u16*)alloc((size_t)BS * ZINN * 2);
  u16* zin_lo = (u16*)alloc((size_t)BS * ZINN * 2);
  u16* Wzh_hi = (u16*)alloc((size_t)HIDN * ZD * 2);
  u16* Wzh_lo = (u16*)alloc((size_t)HIDN * ZD * 2);
  u16* Wzi_hi = (u16*)alloc((size_t)ZINN * ZD * 2);
  u16* Wzi_lo = (u16*)alloc((size_t)ZINN * ZD * 2);
  u16* Wru_hi = (u16*)alloc((size_t)NP * ZINN * 2);
  u16* Wru_lo = (u16*)alloc((size_t)NP * ZINN * 2);
  u16* Wzn_hi = (u16*)alloc((size_t)HIDN * ZINN * 2);
  u16* Wzn_lo = (u16*)alloc((size_t)HIDN * ZINN * 2);
  u16* Whh_hi = (u16*)alloc((size_t)NP * HIDN * 2);
  u16* Whh_lo = (u16*)alloc((size_t)NP * HIDN * 2);
  float* wtok = (float*)alloc((size_t)NP * 3 * 4);
  float* cb0ru = (float*)alloc((size_t)NP * 4);
  float* token = (float*)alloc((size_t)BS * 4 * 4);

  // ---- prep ----
  k_split_whh<<<dim3((NP * HIDN + 255) / 256), 256, 0, stream>>>(W_hh, Whh_hi, Whh_lo);
  k_split<<<dim3((HIDN * ZD + 255) / 256), 256, 0, stream>>>(W_zh, Wzh_hi, Wzh_lo, HIDN * ZD);
  k_split<<<dim3((ZINN * ZD + 255) / 256), 256, 0, stream>>>(W_zi, Wzi_hi, Wzi_lo, ZINN * ZD);
  k_split<<<dim3((BS * ZD + 255) / 256), 256, 0, stream>>>(z, z_hi, z_lo, BS * ZD);
  k_prep_wih<<<dim3((NP * 128 + 255) / 256), 256, 0, stream>>>(
      W_ih, b_ih, b_hh, Wru_hi, Wru_lo, Wzn_hi, Wzn_lo, wtok, cb0ru);
  k_token_init<<<dim3((BS * 4 + 255) / 256), 256, 0, stream>>>(init_input, token);

  // ---- prep GEMMs ----
  // h0 = z @ W_zh^T + b_zh  (f32 + splits)
  k_gemm<true><<<dim3(HIDN / 128, BS / 128), 256, 0, stream>>>(
      z_hi, z_lo, Wzh_hi, Wzh_lo, b_zh, h[0], h_hi[0], h_lo[0], HIDN, ZD);
  // z_in = z @ W_zi^T + b_zi  (splits used by K-fold)
  k_gemm<true><<<dim3(ZINN / 128, BS / 128), 256, 0, stream>>>(
      z_hi, z_lo, Wzi_hi, Wzi_lo, b_zi, zin, zin_hi, zin_lo, ZINN, ZD);
  // C0n = z_in @ Wihz_n^T + b_ih_n  (step-invariant n-gate input part)
  k_gemm<false><<<dim3(HIDN / 128, BS / 128), 256, 0, stream>>>(
      zin_hi, zin_lo, Wzn_hi, Wzn_lo, b_ih + 2048, C0n, nullptr, nullptr, HIDN, ZINN);

  // ---- 32 recurrent steps ----
  for (int t = 0; t < NST; ++t) {
    const int cur = t & 1, nxt = (t + 1) & 1;
    k_fused<<<dim3(NP / 192, BS / 128), 256, 0, stream>>>(
        h_hi[cur], h_lo[cur], zin_hi, zin_lo, Whh_hi, Whh_lo, Wru_hi, Wru_lo,
        C0n, token, wtok, cb0ru, b_hh, h[cur], h[nxt], h_hi[nxt], h_lo[nxt]);
    k_out<<<dim3(BS / 4), 256, 0, stream>>>(h[nxt], W_out, b_out, out, token, t);
  }
  (void)in_sizes; (void)n_in; (void)out_size; (void)ws_size;
}